// Round 1
// baseline (1275.989 us; speedup 1.0000x reference)
//
#include <hip/hip_runtime.h>
#include <math.h>

constexpr int B_ = 4;
constexpr int F_ = 32;
constexpr int H_ = 320;
constexpr int W_ = 320;
constexpr int HW_ = H_ * W_;
constexpr int NS_ = 25;

__device__ __forceinline__ float lrelu(float x) { return x >= 0.f ? x : 0.2f * x; }

// ---------------- q/k: 1x1 conv (32->8) + channel L2 norm ----------------
__global__ __launch_bounds__(256) void qk_kernel(
    const float* __restrict__ x, const float* __restrict__ wq,
    const float* __restrict__ wk, float* __restrict__ q, float* __restrict__ k)
{
  __shared__ float swq[256], swk[256];
  int tid = threadIdx.x;
  swq[tid] = wq[tid];
  swk[tid] = wk[tid];
  __syncthreads();
  int idx = blockIdx.x * 256 + tid;       // b*HW + p
  int b = idx / HW_, p = idx % HW_;
  const float* xp = x + (size_t)b * F_ * HW_ + p;
  float xv[32];
#pragma unroll
  for (int c = 0; c < 32; ++c) xv[c] = xp[(size_t)c * HW_];
  float qv[8], kv[8];
#pragma unroll
  for (int f = 0; f < 8; ++f) {
    float aq = 0.f, ak = 0.f;
#pragma unroll
    for (int c = 0; c < 32; ++c) {
      aq += swq[f * 32 + c] * xv[c];
      ak += swk[f * 32 + c] * xv[c];
    }
    qv[f] = aq; kv[f] = ak;
  }
  float nq = 0.f, nk = 0.f;
#pragma unroll
  for (int f = 0; f < 8; ++f) { nq += qv[f] * qv[f]; nk += kv[f] * kv[f]; }
  nq = 1.f / (sqrtf(nq) + 1e-6f);
  nk = 1.f / (sqrtf(nk) + 1e-6f);
  float* qp = q + (size_t)b * 8 * HW_ + p;
  float* kp = k + (size_t)b * 8 * HW_ + p;
#pragma unroll
  for (int f = 0; f < 8; ++f) {
    qp[(size_t)f * HW_] = qv[f] * nq;
    kp[(size_t)f * HW_] = kv[f] * nk;
  }
}

// ---------------- dot: 25 shifted q·k + smoothing normalization ----------------
__global__ __launch_bounds__(256) void dot_kernel(
    const float* __restrict__ q, const float* __restrict__ k, float* __restrict__ dt)
{
  int idx = blockIdx.x * 256 + threadIdx.x;
  int b = idx / HW_, p = idx % HW_;
  int h = p / W_, w = p % W_;
  float kv[8];
  const float* kp = k + (size_t)b * 8 * HW_ + p;
#pragma unroll
  for (int c = 0; c < 8; ++c) kv[c] = kp[(size_t)c * HW_];
  const float* qb = q + (size_t)b * 8 * HW_;
  float d[25];
#pragma unroll
  for (int i = -2; i <= 2; ++i) {
#pragma unroll
    for (int j = -2; j <= 2; ++j) {
      int s = (i + 2) * 5 + (j + 2);
      int hy = h - i, wx = w - j;
      float acc = 0.f;
      if ((unsigned)hy < (unsigned)H_ && (unsigned)wx < (unsigned)W_) {
        const float* qp = qb + hy * W_ + wx;
#pragma unroll
        for (int c = 0; c < 8; ++c) acc += qp[(size_t)c * HW_] * kv[c];
      }
      d[s] = 1.f - acc;
    }
  }
  float m = d[0];
#pragma unroll
  for (int s = 1; s < 25; ++s) m = fmaxf(m, d[s]);
  float inv = 4.f / (m + 1e-6f);   // /(m+eps)/H_SMOOTH, H_SMOOTH=0.25
  float* dp = dt + (size_t)b * NS_ * HW_ + p;
#pragma unroll
  for (int s = 0; s < 25; ++s) dp[(size_t)s * HW_] = 1.f - d[s] * inv;
}

// ---------------- mixed: grouped 3x3 conv (per-shift), fused shift/mask ----------------
// tile 32x32 px, grid (10,10,B*25), 256 threads, 4 vertical px per thread.
__global__ __launch_bounds__(256) void mixed_kernel(
    const float* __restrict__ q, const float* __restrict__ k,
    const float* __restrict__ dt, const float* __restrict__ wd,
    float* __restrict__ mixed)
{
  __shared__ float diff[8][34][36];
  __shared__ float dts[34][36];
  __shared__ float wsh[81];
  int bs = blockIdx.z;
  int b = bs / NS_, s = bs % NS_;
  int si = s / 5 - 2, sj = s % 5 - 2;
  int h0 = blockIdx.y * 32, w0 = blockIdx.x * 32;
  int tid = threadIdx.x;
  if (tid < 81) wsh[tid] = wd[s * 81 + tid];
  const float* qb = q + (size_t)b * 8 * HW_;
  const float* kb = k + (size_t)b * 8 * HW_;
  float* df = &diff[0][0][0];
  for (int e = tid; e < 8 * 34 * 36; e += 256) {
    int c = e / (34 * 36);
    int rem = e % (34 * 36);
    int r = rem / 36, col = rem % 36;
    float v = 0.f;
    if (col < 34) {
      int gy = h0 + r - 1, gx = w0 + col - 1;
      if ((unsigned)gy < (unsigned)H_ && (unsigned)gx < (unsigned)W_) {
        float kv = kb[(size_t)c * HW_ + gy * W_ + gx];
        int qy = gy - si, qx = gx - sj;
        float qv = ((unsigned)qy < (unsigned)H_ && (unsigned)qx < (unsigned)W_)
                       ? qb[(size_t)c * HW_ + qy * W_ + qx] : 0.f;
        v = qv - kv;   // conv-pad mask == staging bounds check; shift mask == q bounds check
      }
    }
    df[e] = v;
  }
  const float* db = dt + (size_t)(b * NS_ + s) * HW_;
  float* dfl = &dts[0][0];
  for (int e = tid; e < 34 * 36; e += 256) {
    int r = e / 36, col = e % 36;
    float v = 0.f;
    if (col < 34) {
      int gy = h0 + r - 1, gx = w0 + col - 1;
      if ((unsigned)gy < (unsigned)H_ && (unsigned)gx < (unsigned)W_) v = db[gy * W_ + gx];
    }
    dfl[e] = v;
  }
  __syncthreads();
  int x = tid & 31, yg = tid >> 5;   // col 0..31, row-group 0..7 (4 rows each)
  float acc[4] = {0.f, 0.f, 0.f, 0.f};
#pragma unroll
  for (int c = 0; c < 8; ++c) {
    float win[6][3];
#pragma unroll
    for (int r = 0; r < 6; ++r)
#pragma unroll
      for (int dx = 0; dx < 3; ++dx) win[r][dx] = diff[c][yg * 4 + r][x + dx];
#pragma unroll
    for (int dy = 0; dy < 3; ++dy)
#pragma unroll
      for (int dx = 0; dx < 3; ++dx) {
        float wv = wsh[c * 9 + dy * 3 + dx];
#pragma unroll
        for (int p = 0; p < 4; ++p) acc[p] += wv * win[p + dy][dx];
      }
  }
  {
    float win[6][3];
#pragma unroll
    for (int r = 0; r < 6; ++r)
#pragma unroll
      for (int dx = 0; dx < 3; ++dx) win[r][dx] = dts[yg * 4 + r][x + dx];
#pragma unroll
    for (int dy = 0; dy < 3; ++dy)
#pragma unroll
      for (int dx = 0; dx < 3; ++dx) {
        float wv = wsh[72 + dy * 3 + dx];
#pragma unroll
        for (int p = 0; p < 4; ++p) acc[p] += wv * win[p + dy][dx];
      }
  }
  float* mp = mixed + (size_t)(b * NS_ + s) * HW_ + h0 * W_ + w0 + x;
#pragma unroll
  for (int p = 0; p < 4; ++p) mp[(yg * 4 + p) * W_] = acc[p];
}

// ---------------- y: 1x1 conv 25->32 + lrelu (float4 vectorized) ----------------
__global__ __launch_bounds__(256) void y_kernel(
    const float* __restrict__ mixed, const float* __restrict__ wnl, float* __restrict__ y)
{
  __shared__ float sw[NS_ * F_];
  int tid = threadIdx.x;
  for (int e = tid; e < NS_ * F_; e += 256) sw[e] = wnl[e];
  __syncthreads();
  int idx = blockIdx.x * 256 + tid;          // 4-px groups over B*HW/4
  int b = idx / (HW_ / 4);
  int p4 = (idx % (HW_ / 4)) * 4;
  const float4* mp = (const float4*)(mixed + (size_t)b * NS_ * HW_ + p4);
  float4 mv[25];
#pragma unroll
  for (int s = 0; s < 25; ++s) mv[s] = mp[(size_t)s * (HW_ / 4)];
  float* yp = y + (size_t)b * F_ * HW_ + p4;
#pragma unroll
  for (int f = 0; f < F_; ++f) {
    float4 a = {0.f, 0.f, 0.f, 0.f};
#pragma unroll
    for (int s = 0; s < 25; ++s) {
      float wv = sw[f * NS_ + s];
      a.x += wv * mv[s].x; a.y += wv * mv[s].y;
      a.z += wv * mv[s].z; a.w += wv * mv[s].w;
    }
    float4 o;
    o.x = lrelu(a.x); o.y = lrelu(a.y); o.z = lrelu(a.z); o.w = lrelu(a.w);
    *(float4*)(yp + (size_t)f * HW_) = o;
  }
}

// ---------------- generic direct conv (COUT=32) + per-tile stats ----------------
// tile 16x16 out px; 256 thr = 4 co-groups x 64 lanes; each thread 2x2 px, 8 co.
template <int CIN, int KS, int STRIDE, bool UP, bool TWO, int CICHUNK>
__global__ __launch_bounds__(256) void conv_kernel(
    const float* __restrict__ in1, const float* __restrict__ in2,
    const float* __restrict__ wt, float* __restrict__ out,
    float2* __restrict__ partials,
    int IHp, int IWp, int ILH, int ILW, int OH, int OW)
{
  constexpr int IT = 15 * STRIDE + KS;
  constexpr int WIN = STRIDE + KS;
  constexpr int KSS = KS * KS;
  __shared__ float sin_[CICHUNK][IT][IT];
  __shared__ float swt[CICHUNK * KSS * 32];   // [ci][tap][co]
  int tid = threadIdx.x;
  int b = blockIdx.z;
  int h0 = blockIdx.y * 16, w0 = blockIdx.x * 16;
  int g = tid >> 6, lane = tid & 63;
  int ly = lane >> 3, lx = lane & 7;
  float acc[8][2][2];
#pragma unroll
  for (int cc = 0; cc < 8; ++cc)
#pragma unroll
    for (int py = 0; py < 2; ++py)
#pragma unroll
      for (int px = 0; px < 2; ++px) acc[cc][py][px] = 0.f;

  constexpr int NCH = CIN / CICHUNK;
  float* sf = &sin_[0][0][0];
  for (int chunk = 0; chunk < NCH; ++chunk) {
    __syncthreads();
    for (int e = tid; e < CICHUNK * IT * IT; e += 256) {
      int c = e / (IT * IT);
      int rem = e % (IT * IT);
      int r = rem / IT, xx = rem % IT;
      int gy = h0 * STRIDE - 1 + r, gx = w0 * STRIDE - 1 + xx;
      float v = 0.f;
      if ((unsigned)gy < (unsigned)ILH && (unsigned)gx < (unsigned)ILW) {
        int py = UP ? (gy >> 1) : gy;
        int px = UP ? (gx >> 1) : gx;
        int cg = chunk * CICHUNK + c;
        const float* src = in1; int cc = cg;
        if (TWO && cg >= 32) { src = in2; cc = cg - 32; }
        v = src[((size_t)b * 32 + cc) * (size_t)(IHp * IWp) + py * IWp + px];
      }
      sf[e] = v;
    }
    for (int e = tid; e < CICHUNK * KSS * 32; e += 256) {
      int co = e & 31;
      int r2 = e >> 5;
      int t = r2 % KSS, ci = r2 / KSS;
      swt[e] = wt[((size_t)co * CIN + chunk * CICHUNK + ci) * KSS + t];
    }
    __syncthreads();
#pragma unroll 2
    for (int ci = 0; ci < CICHUNK; ++ci) {
      float win[WIN][WIN];
#pragma unroll
      for (int r = 0; r < WIN; ++r)
#pragma unroll
        for (int xx = 0; xx < WIN; ++xx)
          win[r][xx] = sin_[ci][ly * 2 * STRIDE + r][lx * 2 * STRIDE + xx];
#pragma unroll
      for (int t = 0; t < KSS; ++t) {
        const float4* wp4 = (const float4*)&swt[(ci * KSS + t) * 32 + g * 8];
        float4 wa = wp4[0], wb = wp4[1];
        float w8[8] = {wa.x, wa.y, wa.z, wa.w, wb.x, wb.y, wb.z, wb.w};
        int ky = t / KS, kx = t % KS;
#pragma unroll
        for (int cc = 0; cc < 8; ++cc)
#pragma unroll
          for (int py = 0; py < 2; ++py)
#pragma unroll
            for (int px = 0; px < 2; ++px)
              acc[cc][py][px] += w8[cc] * win[py * STRIDE + ky][px * STRIDE + kx];
      }
    }
  }
  // write + per-(b,co,tile) partial stats (deterministic, no atomics)
  int NT = gridDim.x * gridDim.y;
  int tile = blockIdx.y * gridDim.x + blockIdx.x;
#pragma unroll
  for (int cc = 0; cc < 8; ++cc) {
    int co = g * 8 + cc;
    float* op = out + ((size_t)b * 32 + co) * (size_t)(OH * OW);
    float s = 0.f, sq = 0.f;
#pragma unroll
    for (int py = 0; py < 2; ++py)
#pragma unroll
      for (int px = 0; px < 2; ++px) {
        float v = acc[cc][py][px];
        op[(h0 + ly * 2 + py) * OW + (w0 + lx * 2 + px)] = v;
        s += v; sq += v * v;
      }
#pragma unroll
    for (int off = 32; off >= 1; off >>= 1) {
      s += __shfl_xor(s, off);
      sq += __shfl_xor(sq, off);
    }
    if (lane == 0) partials[((size_t)b * 32 + co) * NT + tile] = make_float2(s, sq);
  }
}

// ---------------- stats: reduce tile partials -> mean, rstd ----------------
__global__ __launch_bounds__(256) void stats_kernel(
    const float2* __restrict__ partials, float2* __restrict__ mv, int NT, int N)
{
  int bc = blockIdx.x;
  int tid = threadIdx.x;
  float s = 0.f, sq = 0.f;
  for (int t = tid; t < NT; t += 256) {
    float2 v = partials[(size_t)bc * NT + t];
    s += v.x; sq += v.y;
  }
#pragma unroll
  for (int off = 32; off >= 1; off >>= 1) {
    s += __shfl_xor(s, off);
    sq += __shfl_xor(sq, off);
  }
  __shared__ float rs[4], rq[4];
  int wid = tid >> 6;
  if ((tid & 63) == 0) { rs[wid] = s; rq[wid] = sq; }
  __syncthreads();
  if (tid == 0) {
    s = rs[0] + rs[1] + rs[2] + rs[3];
    sq = rq[0] + rq[1] + rq[2] + rq[3];
    float mean = s / (float)N;
    float var = sq / (float)N - mean * mean;
    mv[bc] = make_float2(mean, rsqrtf(fmaxf(var, 0.f) + 1e-5f));
  }
}

// ---------------- in-place instance-norm + lrelu ----------------
__global__ __launch_bounds__(256) void norm_kernel(
    float* __restrict__ buf, const float2* __restrict__ mv, int plane4, int total4)
{
  int idx = blockIdx.x * 256 + threadIdx.x;
  if (idx >= total4) return;
  int bc = idx / plane4;
  float2 p = mv[bc];
  float4* b4 = (float4*)buf;
  float4 v = b4[idx];
  v.x = lrelu((v.x - p.x) * p.y);
  v.y = lrelu((v.y - p.x) * p.y);
  v.z = lrelu((v.z - p.x) * p.y);
  v.w = lrelu((v.w - p.x) * p.y);
  b4[idx] = v;
}

// ---------------- tail: 3x3 conv 64->1 over concat(d0,u1) ----------------
// tile 32x32 px, 256 thr each 2x2 px, ci chunks of 8.
__global__ __launch_bounds__(256) void tail_kernel(
    const float* __restrict__ d0, const float* __restrict__ u1,
    const float* __restrict__ wt, float* __restrict__ out)
{
  __shared__ float sin_[8][34][34];
  __shared__ float swc[8 * 9];
  int tid = threadIdx.x;
  int b = blockIdx.z, h0 = blockIdx.y * 32, w0 = blockIdx.x * 32;
  int ly = tid >> 4, lx = tid & 15;
  float acc[2][2] = {{0.f, 0.f}, {0.f, 0.f}};
  float* sf = &sin_[0][0][0];
  for (int chunk = 0; chunk < 8; ++chunk) {
    __syncthreads();
    for (int e = tid; e < 8 * 34 * 34; e += 256) {
      int c = e / (34 * 34);
      int rem = e % (34 * 34);
      int r = rem / 34, xx = rem % 34;
      int gy = h0 - 1 + r, gx = w0 - 1 + xx;
      float v = 0.f;
      int cg = chunk * 8 + c;
      const float* src = cg < 32 ? d0 : u1;
      int cc = cg & 31;
      if ((unsigned)gy < (unsigned)H_ && (unsigned)gx < (unsigned)W_)
        v = src[((size_t)b * 32 + cc) * HW_ + gy * W_ + gx];
      sf[e] = v;
    }
    for (int e = tid; e < 8 * 9; e += 256) {
      int ci = e / 9, t = e % 9;
      swc[e] = wt[(chunk * 8 + ci) * 9 + t];
    }
    __syncthreads();
#pragma unroll
    for (int ci = 0; ci < 8; ++ci) {
      float win[4][4];
#pragma unroll
      for (int r = 0; r < 4; ++r)
#pragma unroll
        for (int xx = 0; xx < 4; ++xx) win[r][xx] = sin_[ci][ly * 2 + r][lx * 2 + xx];
#pragma unroll
      for (int t = 0; t < 9; ++t) {
        float wv = swc[ci * 9 + t];
        int ky = t / 3, kx = t % 3;
#pragma unroll
        for (int py = 0; py < 2; ++py)
#pragma unroll
          for (int px = 0; px < 2; ++px)
            acc[py][px] += wv * win[py + ky][px + kx];
      }
    }
  }
  float* op = out + (size_t)b * HW_;
#pragma unroll
  for (int py = 0; py < 2; ++py)
#pragma unroll
    for (int px = 0; px < 2; ++px)
      op[(h0 + ly * 2 + py) * W_ + (w0 + lx * 2 + px)] = acc[py][px];
}

extern "C" void kernel_launch(void* const* d_in, const int* in_sizes, int n_in,
                              void* d_out, int out_size, void* d_ws, size_t ws_size,
                              hipStream_t stream) {
  (void)in_sizes; (void)n_in; (void)out_size; (void)ws_size;
  const float* x       = (const float*)d_in[0];
  const float* w_q     = (const float*)d_in[1];
  const float* w_k     = (const float*)d_in[2];
  const float* w_direct= (const float*)d_in[3];
  const float* w_nl    = (const float*)d_in[4];
  const float* w_head  = (const float*)d_in[5];
  const float* w_down1 = (const float*)d_in[6];
  const float* w_down2 = (const float*)d_in[7];
  const float* w_e0    = (const float*)d_in[8];
  const float* w_up2   = (const float*)d_in[9];
  const float* w_up1   = (const float*)d_in[10];
  const float* w_tail  = (const float*)d_in[11];
  float* out = (float*)d_out;

  // workspace layout (floats), with liveness-based aliasing (total ~172.5 MB)
  float* ws   = (float*)d_ws;
  float* qb   = ws;                       // 3,276,800
  float* kb   = qb + 3276800;             // 3,276,800
  float* bufC = kb + 3276800;             // 13,107,200 : dot -> y -> u1
  float* bufD = bufC + 13107200;          // 10,240,000 : mixed -> d2,e0
  float* d0b  = bufD + 10240000;          // 13,107,200
  float2* partials = (float2*)(d0b + 13107200);  // 51,200 float2
  float2* mv = partials + 51200;          // 128 float2

  float* dotb = bufC;
  float* yb   = bufC;
  float* u1b  = bufC;
  float* mixedb = bufD;
  float* d2b  = bufD;
  float* e0b  = bufD + 819200;
  float* d1b  = qb;
  float* u2b  = kb;

  qk_kernel<<<1600, 256, 0, stream>>>(x, w_q, w_k, qb, kb);
  dot_kernel<<<1600, 256, 0, stream>>>(qb, kb, dotb);
  mixed_kernel<<<dim3(10, 10, 100), 256, 0, stream>>>(qb, kb, dotb, w_direct, mixedb);
  y_kernel<<<400, 256, 0, stream>>>(mixedb, w_nl, yb);

  // d0 = lrelu(inorm(conv3x3(y)))   320x320
  conv_kernel<32, 3, 1, false, false, 16><<<dim3(20, 20, 4), 256, 0, stream>>>(
      yb, nullptr, w_head, d0b, partials, 320, 320, 320, 320, 320, 320);
  stats_kernel<<<128, 256, 0, stream>>>(partials, mv, 400, 102400);
  norm_kernel<<<12800, 256, 0, stream>>>(d0b, mv, 25600, 3276800);

  // d1 = lrelu(inorm(conv4x4 s2(d0)))  160x160
  conv_kernel<32, 4, 2, false, false, 8><<<dim3(10, 10, 4), 256, 0, stream>>>(
      d0b, nullptr, w_down1, d1b, partials, 320, 320, 320, 320, 160, 160);
  stats_kernel<<<128, 256, 0, stream>>>(partials, mv, 100, 25600);
  norm_kernel<<<3200, 256, 0, stream>>>(d1b, mv, 6400, 819200);

  // d2 = lrelu(inorm(conv4x4 s2(d1)))  80x80
  conv_kernel<32, 4, 2, false, false, 8><<<dim3(5, 5, 4), 256, 0, stream>>>(
      d1b, nullptr, w_down2, d2b, partials, 160, 160, 160, 160, 80, 80);
  stats_kernel<<<128, 256, 0, stream>>>(partials, mv, 25, 6400);
  norm_kernel<<<800, 256, 0, stream>>>(d2b, mv, 1600, 204800);

  // e0 = lrelu(inorm(conv3x3(d2)))  80x80
  conv_kernel<32, 3, 1, false, false, 16><<<dim3(5, 5, 4), 256, 0, stream>>>(
      d2b, nullptr, w_e0, e0b, partials, 80, 80, 80, 80, 80, 80);
  stats_kernel<<<128, 256, 0, stream>>>(partials, mv, 25, 6400);
  norm_kernel<<<800, 256, 0, stream>>>(e0b, mv, 1600, 204800);

  // u2 = lrelu(inorm(conv3x3(up2x(e0))))  160x160
  conv_kernel<32, 3, 1, true, false, 16><<<dim3(10, 10, 4), 256, 0, stream>>>(
      e0b, nullptr, w_up2, u2b, partials, 80, 80, 160, 160, 160, 160);
  stats_kernel<<<128, 256, 0, stream>>>(partials, mv, 100, 25600);
  norm_kernel<<<3200, 256, 0, stream>>>(u2b, mv, 6400, 819200);

  // u1 = lrelu(inorm(conv3x3(up2x(concat(d1,u2)))))  320x320
  conv_kernel<64, 3, 1, true, true, 16><<<dim3(20, 20, 4), 256, 0, stream>>>(
      d1b, u2b, w_up1, u1b, partials, 160, 160, 320, 320, 320, 320);
  stats_kernel<<<128, 256, 0, stream>>>(partials, mv, 400, 102400);
  norm_kernel<<<12800, 256, 0, stream>>>(u1b, mv, 25600, 3276800);

  // att = conv3x3(concat(d0,u1)) -> out
  tail_kernel<<<dim3(10, 10, 4), 256, 0, stream>>>(d0b, u1b, w_tail, out);
}

// Round 3
// 704.458 us; speedup vs baseline: 1.8113x; 1.8113x over previous
//
#include <hip/hip_runtime.h>
#include <hip/hip_bf16.h>
#include <math.h>

constexpr int B_ = 4;
constexpr int F_ = 32;
constexpr int H_ = 320;
constexpr int W_ = 320;
constexpr int HW_ = H_ * W_;
constexpr int NS_ = 25;

typedef short short8 __attribute__((ext_vector_type(8)));
typedef short short4v __attribute__((ext_vector_type(4)));
typedef float f32x4 __attribute__((ext_vector_type(4)));
typedef __bf16 bf16x8 __attribute__((ext_vector_type(8)));

__device__ __forceinline__ float lrelu(float x) { return x >= 0.f ? x : 0.2f * x; }

__device__ __forceinline__ short bf16_of(float f) {
  __hip_bfloat16 h = __float2bfloat16(f);
  return __builtin_bit_cast(short, h);
}
__device__ __forceinline__ float f_of_bf16(short s) {
  unsigned int u = ((unsigned int)(unsigned short)s) << 16;
  return __builtin_bit_cast(float, u);
}

// MFMA via builtin (backend handles MAI hazards + waitcnt).
// Layouts (guide §3, m89-verified D): a[j]=A[lane&15][k], b[j]=B[k][lane&15],
// d[r]=D[(lane>>4)*4+r][lane&15]; k-map identical for A/B => our k ordering
// (t*CIN+ci) is self-consistent regardless of HW k permutation.
__device__ __forceinline__ void mfma16(f32x4& acc, short8 a, short8 b) {
  acc = __builtin_amdgcn_mfma_f32_16x16x32_bf16(
      __builtin_bit_cast(bf16x8, a), __builtin_bit_cast(bf16x8, b), acc, 0, 0, 0);
}

// ---------------- q/k: 1x1 conv (32->8) + channel L2 norm (fp32) ----------------
__global__ __launch_bounds__(256) void qk_kernel(
    const float* __restrict__ x, const float* __restrict__ wq,
    const float* __restrict__ wk, float* __restrict__ q, float* __restrict__ k)
{
  __shared__ float swq[256], swk[256];
  int tid = threadIdx.x;
  swq[tid] = wq[tid];
  swk[tid] = wk[tid];
  __syncthreads();
  int idx = blockIdx.x * 256 + tid;
  int b = idx / HW_, p = idx % HW_;
  const float* xp = x + (size_t)b * F_ * HW_ + p;
  float xv[32];
#pragma unroll
  for (int c = 0; c < 32; ++c) xv[c] = xp[(size_t)c * HW_];
  float qv[8], kv[8];
#pragma unroll
  for (int f = 0; f < 8; ++f) {
    float aq = 0.f, ak = 0.f;
#pragma unroll
    for (int c = 0; c < 32; ++c) {
      aq += swq[f * 32 + c] * xv[c];
      ak += swk[f * 32 + c] * xv[c];
    }
    qv[f] = aq; kv[f] = ak;
  }
  float nq = 0.f, nk = 0.f;
#pragma unroll
  for (int f = 0; f < 8; ++f) { nq += qv[f] * qv[f]; nk += kv[f] * kv[f]; }
  nq = 1.f / (sqrtf(nq) + 1e-6f);
  nk = 1.f / (sqrtf(nk) + 1e-6f);
  float* qp = q + (size_t)b * 8 * HW_ + p;
  float* kp = k + (size_t)b * 8 * HW_ + p;
#pragma unroll
  for (int f = 0; f < 8; ++f) {
    qp[(size_t)f * HW_] = qv[f] * nq;
    kp[(size_t)f * HW_] = kv[f] * nk;
  }
}

// ---------------- dot: 25 shifted q·k + smoothing normalization (fp32) ----------------
__global__ __launch_bounds__(256) void dot_kernel(
    const float* __restrict__ q, const float* __restrict__ k, float* __restrict__ dt)
{
  int idx = blockIdx.x * 256 + threadIdx.x;
  int b = idx / HW_, p = idx % HW_;
  int h = p / W_, w = p % W_;
  float kv[8];
  const float* kp = k + (size_t)b * 8 * HW_ + p;
#pragma unroll
  for (int c = 0; c < 8; ++c) kv[c] = kp[(size_t)c * HW_];
  const float* qb = q + (size_t)b * 8 * HW_;
  float d[25];
#pragma unroll
  for (int i = -2; i <= 2; ++i) {
#pragma unroll
    for (int j = -2; j <= 2; ++j) {
      int s = (i + 2) * 5 + (j + 2);
      int hy = h - i, wx = w - j;
      float acc = 0.f;
      if ((unsigned)hy < (unsigned)H_ && (unsigned)wx < (unsigned)W_) {
        const float* qp = qb + hy * W_ + wx;
#pragma unroll
        for (int c = 0; c < 8; ++c) acc += qp[(size_t)c * HW_] * kv[c];
      }
      d[s] = 1.f - acc;
    }
  }
  float m = d[0];
#pragma unroll
  for (int s = 1; s < 25; ++s) m = fmaxf(m, d[s]);
  float inv = 4.f / (m + 1e-6f);
  float* dp = dt + (size_t)b * NS_ * HW_ + p;
#pragma unroll
  for (int s = 0; s < 25; ++s) dp[(size_t)s * HW_] = 1.f - d[s] * inv;
}

// ---------------- mixed: grouped 3x3 conv (per-shift), fused shift/mask (fp32) ----------------
__global__ __launch_bounds__(256) void mixed_kernel(
    const float* __restrict__ q, const float* __restrict__ k,
    const float* __restrict__ dt, const float* __restrict__ wd,
    float* __restrict__ mixed)
{
  __shared__ float diff[8][34][36];
  __shared__ float dts[34][36];
  __shared__ float wsh[81];
  int bs = blockIdx.z;
  int b = bs / NS_, s = bs % NS_;
  int si = s / 5 - 2, sj = s % 5 - 2;
  int h0 = blockIdx.y * 32, w0 = blockIdx.x * 32;
  int tid = threadIdx.x;
  if (tid < 81) wsh[tid] = wd[s * 81 + tid];
  const float* qb = q + (size_t)b * 8 * HW_;
  const float* kb = k + (size_t)b * 8 * HW_;
  float* df = &diff[0][0][0];
  for (int e = tid; e < 8 * 34 * 36; e += 256) {
    int c = e / (34 * 36);
    int rem = e % (34 * 36);
    int r = rem / 36, col = rem % 36;
    float v = 0.f;
    if (col < 34) {
      int gy = h0 + r - 1, gx = w0 + col - 1;
      if ((unsigned)gy < (unsigned)H_ && (unsigned)gx < (unsigned)W_) {
        float kv = kb[(size_t)c * HW_ + gy * W_ + gx];
        int qy = gy - si, qx = gx - sj;
        float qv = ((unsigned)qy < (unsigned)H_ && (unsigned)qx < (unsigned)W_)
                       ? qb[(size_t)c * HW_ + qy * W_ + qx] : 0.f;
        v = qv - kv;
      }
    }
    df[e] = v;
  }
  const float* db = dt + (size_t)(b * NS_ + s) * HW_;
  float* dfl = &dts[0][0];
  for (int e = tid; e < 34 * 36; e += 256) {
    int r = e / 36, col = e % 36;
    float v = 0.f;
    if (col < 34) {
      int gy = h0 + r - 1, gx = w0 + col - 1;
      if ((unsigned)gy < (unsigned)H_ && (unsigned)gx < (unsigned)W_) v = db[gy * W_ + gx];
    }
    dfl[e] = v;
  }
  __syncthreads();
  int x = tid & 31, yg = tid >> 5;
  float acc[4] = {0.f, 0.f, 0.f, 0.f};
#pragma unroll
  for (int c = 0; c < 8; ++c) {
    float win[6][3];
#pragma unroll
    for (int r = 0; r < 6; ++r)
#pragma unroll
      for (int dx = 0; dx < 3; ++dx) win[r][dx] = diff[c][yg * 4 + r][x + dx];
#pragma unroll
    for (int dy = 0; dy < 3; ++dy)
#pragma unroll
      for (int dx = 0; dx < 3; ++dx) {
        float wv = wsh[c * 9 + dy * 3 + dx];
#pragma unroll
        for (int p = 0; p < 4; ++p) acc[p] += wv * win[p + dy][dx];
      }
  }
  {
    float win[6][3];
#pragma unroll
    for (int r = 0; r < 6; ++r)
#pragma unroll
      for (int dx = 0; dx < 3; ++dx) win[r][dx] = dts[yg * 4 + r][x + dx];
#pragma unroll
    for (int dy = 0; dy < 3; ++dy)
#pragma unroll
      for (int dx = 0; dx < 3; ++dx) {
        float wv = wsh[72 + dy * 3 + dx];
#pragma unroll
        for (int p = 0; p < 4; ++p) acc[p] += wv * win[p + dy][dx];
      }
  }
  float* mp = mixed + (size_t)(b * NS_ + s) * HW_ + h0 * W_ + w0 + x;
#pragma unroll
  for (int p = 0; p < 4; ++p) mp[(yg * 4 + p) * W_] = acc[p];
}

// ---------------- y: 1x1 conv 25->32 + lrelu -> padded NHWC bf16 ----------------
__global__ __launch_bounds__(256) void y_kernel(
    const float* __restrict__ mixed, const float* __restrict__ wnl,
    __hip_bfloat16* __restrict__ yb)
{
  __shared__ float sw[32 * 25];
  int tid = threadIdx.x;
  for (int e = tid; e < 800; e += 256) sw[e] = wnl[e];
  __syncthreads();
  int idx = blockIdx.x * 256 + tid;
  int b = idx / HW_, pp = idx % HW_;
  const float* mp = mixed + (size_t)b * NS_ * HW_ + pp;
  float m[25];
#pragma unroll
  for (int s = 0; s < 25; ++s) m[s] = mp[(size_t)s * HW_];
  int y = pp / W_, x = pp % W_;
  short8* dst = (short8*)(yb + ((size_t)b * 324 * 324 + (size_t)(y + 2) * 324 + (x + 2)) * 32);
#pragma unroll
  for (int f0 = 0; f0 < 32; f0 += 8) {
    short8 o;
#pragma unroll
    for (int j = 0; j < 8; ++j) {
      int f = f0 + j;
      float a = 0.f;
#pragma unroll
      for (int s = 0; s < 25; ++s) a += sw[f * 25 + s] * m[s];
      o[j] = bf16_of(lrelu(a));
    }
    dst[f0 >> 3] = o;
  }
}

// ---------------- zero the 2-px halo of a padded NHWC bf16 buffer ----------------
__global__ void halo_zero(__hip_bfloat16* buf, int H, int W) {
  int Wp = W + 4, Hp = H + 4;
  int nt = 4 * Wp + 4 * H;
  int idx = blockIdx.x * 256 + threadIdx.x;
  int b = blockIdx.y;
  if (idx >= nt) return;
  int y, x;
  if (idx < 2 * Wp) { y = idx / Wp; x = idx % Wp; }
  else if (idx < 4 * Wp) { int r = idx - 2 * Wp; y = Hp - 2 + r / Wp; x = r % Wp; }
  else { int r = idx - 4 * Wp; int row = r >> 2; int c = r & 3; y = 2 + row; x = (c < 2) ? c : (Wp - 4 + c); }
  int4* p = (int4*)(buf + ((size_t)b * Hp * Wp + (size_t)y * Wp + x) * 32);
  int4 z = {0, 0, 0, 0};
  p[0] = z; p[1] = z; p[2] = z; p[3] = z;
}

// ---------------- MFMA implicit-GEMM conv over padded NHWC bf16 ----------------
// Block: 4 waves; wave w -> output row oy=by*4+w, cols ox0..ox0+16*NPW.
// Wave computes D[32co][16*NPW px]; K = taps*CIN. UP: fused up2x. TWO: concat input.
template <int CIN, int KS, int STRIDE, bool UP, bool TWO, int NPW, bool TAIL>
__global__ __launch_bounds__(256) void mconv(
    const __hip_bfloat16* __restrict__ in1, const __hip_bfloat16* __restrict__ in2,
    const float* __restrict__ wt,
    __hip_bfloat16* __restrict__ outb, float* __restrict__ outf,
    float2* __restrict__ partials,
    int Hin, int Win, int Hout, int Wout)
{
  constexpr int KSS = KS * KS;
  constexpr int K = KSS * CIN;
  constexpr int AK = K + 8;                 // +16B row pad -> ~2-way LDS aliasing (free)
  __shared__ short lA[32 * AK];
  int tid = threadIdx.x;
  for (int e = tid; e < 32 * K; e += 256) {
    int co = e / K, kk = e - co * K;
    int t = kk / CIN, ci = kk - t * CIN;
    float v = 0.f;
    if (!TAIL || co == 0) v = wt[((size_t)co * CIN + ci) * KSS + t];
    lA[co * AK + kk] = bf16_of(v);
  }
  __syncthreads();

  int wid = tid >> 6, lane = tid & 63;
  int p = lane & 15, q = lane >> 4;
  int b = blockIdx.z;
  int oy = blockIdx.y * 4 + wid;
  int ox0 = blockIdx.x * (16 * NPW);

  size_t RS = (size_t)(Win + 4) * 64;       // bytes per padded input row
  size_t IMG = (size_t)(Hin + 4) * RS;
  const char* base1 = (const char*)in1 + (size_t)b * IMG;
  const char* base2 = TWO ? ((const char*)in2 + (size_t)b * IMG) : nullptr;

  int colB[NPW][KS];
#pragma unroll
  for (int s = 0; s < NPW; ++s)
#pragma unroll
    for (int dx = 0; dx < KS; ++dx) {
      int ox = ox0 + s * 16 + p;
      int ix = ox * STRIDE - 1 + dx;
      int sx = UP ? (ix >> 1) : ix;
      colB[s][dx] = (sx + 2) * 64 + q * 16;
    }
  int aBase = p * AK + q * 8;

  f32x4 acc[NPW][2];
#pragma unroll
  for (int s = 0; s < NPW; ++s)
#pragma unroll
    for (int h = 0; h < 2; ++h) acc[s][h] = (f32x4){0.f, 0.f, 0.f, 0.f};

#pragma unroll
  for (int dy = 0; dy < KS; ++dy) {
    int iy = oy * STRIDE - 1 + dy;
    int sy = UP ? (iy >> 1) : iy;
    const char* r1 = base1 + (size_t)(sy + 2) * RS;
    const char* r2 = TWO ? (base2 + (size_t)(sy + 2) * RS) : nullptr;
#pragma unroll
    for (int dx = 0; dx < KS; ++dx) {
      int t = dy * KS + dx;
      {
        short8 a0 = *(const short8*)&lA[aBase + t * CIN];
        short8 a1 = *(const short8*)&lA[aBase + 16 * AK + t * CIN];
        short8 bf[NPW];
#pragma unroll
        for (int s = 0; s < NPW; ++s) bf[s] = *(const short8*)(r1 + colB[s][dx]);
#pragma unroll
        for (int s = 0; s < NPW; ++s) {
          mfma16(acc[s][0], a0, bf[s]);
          mfma16(acc[s][1], a1, bf[s]);
        }
      }
      if (TWO) {
        short8 a0 = *(const short8*)&lA[aBase + t * CIN + 32];
        short8 a1 = *(const short8*)&lA[aBase + 16 * AK + t * CIN + 32];
        short8 bf[NPW];
#pragma unroll
        for (int s = 0; s < NPW; ++s) bf[s] = *(const short8*)(r2 + colB[s][dx]);
#pragma unroll
        for (int s = 0; s < NPW; ++s) {
          mfma16(acc[s][0], a0, bf[s]);
          mfma16(acc[s][1], a1, bf[s]);
        }
      }
    }
  }

  if constexpr (TAIL) {
    if (q == 0) {
#pragma unroll
      for (int s = 0; s < NPW; ++s)
        outf[(size_t)b * HW_ + (size_t)oy * W_ + (ox0 + s * 16 + p)] = acc[s][0][0];
    }
  } else {
    size_t RSO = (size_t)(Wout + 4) * 64;
    char* ob = (char*)outb + (size_t)b * (Hout + 4) * RSO + (size_t)(oy + 2) * RSO;
#pragma unroll
    for (int s = 0; s < NPW; ++s) {
      char* pxp = ob + (size_t)(ox0 + s * 16 + p + 2) * 64;
#pragma unroll
      for (int h = 0; h < 2; ++h) {
        short4v w4;
#pragma unroll
        for (int r = 0; r < 4; ++r) w4[r] = bf16_of(acc[s][h][r]);
        *(short4v*)(pxp + h * 32 + q * 8) = w4;
      }
    }
    float sv[2][4], qv[2][4];
#pragma unroll
    for (int h = 0; h < 2; ++h)
#pragma unroll
      for (int r = 0; r < 4; ++r) {
        float ts = 0.f, tq = 0.f;
#pragma unroll
        for (int s = 0; s < NPW; ++s) { float v = acc[s][h][r]; ts += v; tq += v * v; }
        sv[h][r] = ts; qv[h][r] = tq;
      }
#pragma unroll
    for (int off = 1; off <= 8; off <<= 1)
#pragma unroll
      for (int h = 0; h < 2; ++h)
#pragma unroll
        for (int r = 0; r < 4; ++r) {
          sv[h][r] += __shfl_xor(sv[h][r], off);
          qv[h][r] += __shfl_xor(qv[h][r], off);
        }
    if (p == 0) {
      int nbx = gridDim.x;
      int NT = Hout * nbx;
      int tile = oy * nbx + blockIdx.x;
#pragma unroll
      for (int h = 0; h < 2; ++h)
#pragma unroll
        for (int r = 0; r < 4; ++r) {
          int co = h * 16 + q * 4 + r;
          partials[(size_t)(b * 32 + co) * NT + tile] = make_float2(sv[h][r], qv[h][r]);
        }
    }
  }
}

// ---------------- stats: reduce tile partials -> mean, rstd ----------------
__global__ __launch_bounds__(256) void stats_kernel(
    const float2* __restrict__ partials, float2* __restrict__ mv, int NT, int N)
{
  int bc = blockIdx.x;
  int tid = threadIdx.x;
  float s = 0.f, sq = 0.f;
  for (int t = tid; t < NT; t += 256) {
    float2 v = partials[(size_t)bc * NT + t];
    s += v.x; sq += v.y;
  }
#pragma unroll
  for (int off = 32; off >= 1; off >>= 1) {
    s += __shfl_xor(s, off);
    sq += __shfl_xor(sq, off);
  }
  __shared__ float rs[4], rq[4];
  int wid = tid >> 6;
  if ((tid & 63) == 0) { rs[wid] = s; rq[wid] = sq; }
  __syncthreads();
  if (tid == 0) {
    s = rs[0] + rs[1] + rs[2] + rs[3];
    sq = rq[0] + rq[1] + rq[2] + rq[3];
    float mean = s / (float)N;
    float var = sq / (float)N - mean * mean;
    mv[bc] = make_float2(mean, rsqrtf(fmaxf(var, 0.f) + 1e-5f));
  }
}

// ---------------- in-place instance-norm + lrelu on padded NHWC bf16 ----------------
__global__ __launch_bounds__(256) void bnorm_kernel(
    __hip_bfloat16* __restrict__ buf, const float2* __restrict__ mv, int H, int W)
{
  int idx = blockIdx.x * 256 + threadIdx.x;
  int total = B_ * H * W * 4;
  if (idx >= total) return;
  int g = idx & 3;
  int px = idx >> 2;
  int x = px % W; int t = px / W; int y = t % H; int b = t / H;
  int Wp = W + 4;
  size_t off = ((size_t)b * (H + 4) * Wp + (size_t)(y + 2) * Wp + (x + 2)) * 32 + g * 8;
  short8* ptr = (short8*)(buf + off);
  short8 v = *ptr;
  const float2* m = mv + b * 32 + g * 8;
  short8 o;
#pragma unroll
  for (int j = 0; j < 8; ++j) {
    float2 p2 = m[j];
    float f = f_of_bf16(v[j]);
    f = lrelu((f - p2.x) * p2.y);
    o[j] = bf16_of(f);
  }
  *ptr = o;
}

extern "C" void kernel_launch(void* const* d_in, const int* in_sizes, int n_in,
                              void* d_out, int out_size, void* d_ws, size_t ws_size,
                              hipStream_t stream) {
  (void)in_sizes; (void)n_in; (void)out_size; (void)ws_size;
  const float* x       = (const float*)d_in[0];
  const float* w_q     = (const float*)d_in[1];
  const float* w_k     = (const float*)d_in[2];
  const float* w_direct= (const float*)d_in[3];
  const float* w_nl    = (const float*)d_in[4];
  const float* w_head  = (const float*)d_in[5];
  const float* w_down1 = (const float*)d_in[6];
  const float* w_down2 = (const float*)d_in[7];
  const float* w_e0    = (const float*)d_in[8];
  const float* w_up2   = (const float*)d_in[9];
  const float* w_up1   = (const float*)d_in[10];
  const float* w_tail  = (const float*)d_in[11];
  float* out = (float*)d_out;

  // ---- workspace layout (bytes), liveness-aliased, total ~138.3 MB ----
  char* ws = (char*)d_ws;
  float* qb   = (float*)(ws + 0);                    // 13.11 MB (fp32)
  float* kb   = (float*)(ws + 13107200);             // 13.11 MB
  float* dotb = (float*)(ws + 26214400);             // 40.96 MB
  float* mixedb = (float*)(ws + 67174400);           // 40.96 MB
  __hip_bfloat16* yb  = (__hip_bfloat16*)(ws + 26214400);   // aliases dot (dead after mixed)
  __hip_bfloat16* d0b = (__hip_bfloat16*)(ws + 67174400);   // aliases mixed (dead after y)
  __hip_bfloat16* d1b = (__hip_bfloat16*)(ws + 0);          // aliases q (dead after mixed)
  __hip_bfloat16* d2b = (__hip_bfloat16*)(ws + 6885376);
  __hip_bfloat16* e0b = (__hip_bfloat16*)(ws + 8691712);
  __hip_bfloat16* u2b = (__hip_bfloat16*)(ws + 13107200);   // aliases k
  __hip_bfloat16* u1b = (__hip_bfloat16*)(ws + 108134400);  // 26.87 MB fresh
  float2* partials = (float2*)(ws + 135008256);      // 3.28 MB
  float2* mv       = (float2*)(ws + 138285056);      // 1 KB

  // ---- fp32 front-end ----
  qk_kernel<<<1600, 256, 0, stream>>>(x, w_q, w_k, qb, kb);
  dot_kernel<<<1600, 256, 0, stream>>>(qb, kb, dotb);
  mixed_kernel<<<dim3(10, 10, 100), 256, 0, stream>>>(qb, kb, dotb, w_direct, mixedb);

  // halos (after last reader of the aliased region; before producer writes interior)
  halo_zero<<<dim3(11, 4), 256, 0, stream>>>(yb, 320, 320);
  halo_zero<<<dim3(6, 4), 256, 0, stream>>>(d1b, 160, 160);
  halo_zero<<<dim3(3, 4), 256, 0, stream>>>(d2b, 80, 80);
  halo_zero<<<dim3(3, 4), 256, 0, stream>>>(e0b, 80, 80);
  halo_zero<<<dim3(6, 4), 256, 0, stream>>>(u2b, 160, 160);
  halo_zero<<<dim3(11, 4), 256, 0, stream>>>(u1b, 320, 320);

  y_kernel<<<1600, 256, 0, stream>>>(mixedb, w_nl, yb);
  halo_zero<<<dim3(11, 4), 256, 0, stream>>>(d0b, 320, 320);  // mixed dead now

  // ---- bf16 MFMA conv stack ----
  // d0 = lrelu(inorm(conv3x3(y)))  320x320
  mconv<32, 3, 1, false, false, 2, false><<<dim3(10, 80, 4), 256, 0, stream>>>(
      yb, nullptr, w_head, d0b, nullptr, partials, 320, 320, 320, 320);
  stats_kernel<<<128, 256, 0, stream>>>(partials, mv, 3200, 102400);
  bnorm_kernel<<<6400, 256, 0, stream>>>(d0b, mv, 320, 320);

  // d1 = lrelu(inorm(conv4x4 s2(d0)))  160x160
  mconv<32, 4, 2, false, false, 2, false><<<dim3(5, 40, 4), 256, 0, stream>>>(
      d0b, nullptr, w_down1, d1b, nullptr, partials, 320, 320, 160, 160);
  stats_kernel<<<128, 256, 0, stream>>>(partials, mv, 800, 25600);
  bnorm_kernel<<<1600, 256, 0, stream>>>(d1b, mv, 160, 160);

  // d2 = lrelu(inorm(conv4x4 s2(d1)))  80x80
  mconv<32, 4, 2, false, false, 1, false><<<dim3(5, 20, 4), 256, 0, stream>>>(
      d1b, nullptr, w_down2, d2b, nullptr, partials, 160, 160, 80, 80);
  stats_kernel<<<128, 256, 0, stream>>>(partials, mv, 400, 6400);
  bnorm_kernel<<<400, 256, 0, stream>>>(d2b, mv, 80, 80);

  // e0 = lrelu(inorm(conv3x3(d2)))  80x80
  mconv<32, 3, 1, false, false, 1, false><<<dim3(5, 20, 4), 256, 0, stream>>>(
      d2b, nullptr, w_e0, e0b, nullptr, partials, 80, 80, 80, 80);
  stats_kernel<<<128, 256, 0, stream>>>(partials, mv, 400, 6400);
  bnorm_kernel<<<400, 256, 0, stream>>>(e0b, mv, 80, 80);

  // u2 = lrelu(inorm(conv3x3(up2x(e0))))  160x160
  mconv<32, 3, 1, true, false, 2, false><<<dim3(5, 40, 4), 256, 0, stream>>>(
      e0b, nullptr, w_up2, u2b, nullptr, partials, 80, 80, 160, 160);
  stats_kernel<<<128, 256, 0, stream>>>(partials, mv, 800, 25600);
  bnorm_kernel<<<1600, 256, 0, stream>>>(u2b, mv, 160, 160);

  // u1 = lrelu(inorm(conv3x3(up2x(concat(d1,u2)))))  320x320
  mconv<64, 3, 1, true, true, 2, false><<<dim3(10, 80, 4), 256, 0, stream>>>(
      d1b, u2b, w_up1, u1b, nullptr, partials, 160, 160, 320, 320);
  stats_kernel<<<128, 256, 0, stream>>>(partials, mv, 3200, 102400);
  bnorm_kernel<<<6400, 256, 0, stream>>>(u1b, mv, 320, 320);

  // att = conv3x3(concat(d0,u1)) -> out (fp32, unpadded)
  mconv<64, 3, 1, false, true, 2, true><<<dim3(10, 80, 4), 256, 0, stream>>>(
      d0b, u1b, w_tail, nullptr, out, nullptr, 320, 320, 320, 320);
}